// Round 9
// baseline (176.417 us; speedup 1.0000x reference)
//
#include <hip/hip_runtime.h>
#include <math.h>

// Problem constants (fixed by setup_inputs)
#define NP 8192      // pred vertices
#define NG 12000     // gt vertices
#define NFP 16384    // pred faces
#define NFG 24000    // gt faces
#define EPSF 1e-6f

// uniform grid for NN: 16^3 cells over [0,1]^3, ~3 gt / ~2 pred per cell
#define GR 16
#define NC (GR*GR*GR)        // 4096
#define HCELL 0.0625f        // 1/16, exact power of two
#define QL 16                // lanes cooperating per NN query
#define QPB (256 / QL)       // 16 queries per block
#define PRED_QBLOCKS (NP / QPB)               // 512
#define GT_QBLOCKS (NG / QPB)                 // 750

// ---- workspace layout (bytes) ----
static constexpr size_t OFF_STARTP = 0;        // (NC+1) u32 cell start (pred), [NC]=NP
static constexpr size_t OFF_STARTG = 16640;    // (NC+1) u32 cell start (gt), [NC]=NG
static constexpr size_t OFF_SORTP  = 33280;    // 8192  float4 (x,y,z,idx-as-float-bits)
static constexpr size_t OFF_SORTG  = 164352;   // 12000 float4
static constexpr size_t OFF_KEYS   = 356352;   // 8192 u64 pred NN keys (d2bits<<32)|idx
static constexpr size_t OFF_COLP   = 421888;   // 750 f32 gt-side per-block partials
static constexpr size_t OFF_GTN    = 424960;   // NG*3 f32 gt normal accum (raw)
static constexpr size_t OFF_PNN    = 568960;   // NP*3 f32 pred normal accum
static constexpr size_t OFF_NSUM   = 667264;   // NP*3 f32 laplacian neighbor sum
static constexpr size_t OFF_DEG    = 765568;   // NP   f32 laplacian degree
#define N_ZERO 93344   // floats gtn..deg (contiguous)

__device__ __forceinline__ int cell_of(float x) {
    int c = (int)(x * (float)GR);
    return min(max(c, 0), GR - 1);
}

// histogram + exclusive scan + cell-ordered scatter of one point set
// (one 1024-thread block; LDS h[] doubles as scan result then scatter cursor)
__device__ __forceinline__ void hist_scan_scatter(const float* __restrict__ pts, int n,
                                                  unsigned* __restrict__ start,
                                                  float4* __restrict__ sorted,
                                                  unsigned* h, unsigned* ps) {
    int t = threadIdx.x;
    for (int i = t; i < NC; i += 1024) h[i] = 0u;
    __syncthreads();
    for (int i = t; i < n; i += 1024) {
        int c = (cell_of(pts[3*i+2]) * GR + cell_of(pts[3*i+1])) * GR + cell_of(pts[3*i]);
        atomicAdd(&h[c], 1u);
    }
    __syncthreads();
    unsigned a0 = h[4*t], a1 = h[4*t+1], a2 = h[4*t+2], a3 = h[4*t+3];
    unsigned tsum = a0 + a1 + a2 + a3;
    ps[t] = tsum; __syncthreads();
    for (int off = 1; off < 1024; off <<= 1) {
        unsigned v = (t >= off) ? ps[t - off] : 0u;
        __syncthreads();
        ps[t] += v;
        __syncthreads();
    }
    unsigned ex = ps[t] - tsum;
    h[4*t] = ex; h[4*t+1] = ex + a0; h[4*t+2] = ex + a0 + a1; h[4*t+3] = ex + a0 + a1 + a2;
    __syncthreads();
    for (int i = t; i < NC; i += 1024) start[i] = h[i];
    if (t == 0) start[NC] = (unsigned)n;   // end sentinel: end[c] == start[c+1]
    __syncthreads();
    // scatter using h as live cursors (start[] already safely in global)
    for (int i = t; i < n; i += 1024) {
        float x = pts[3*i], y = pts[3*i+1], z = pts[3*i+2];
        int c = (cell_of(z) * GR + cell_of(y)) * GR + cell_of(x);
        unsigned pos = atomicAdd(&h[c], 1u);
        sorted[pos] = make_float4(x, y, z, __int_as_float(i));
    }
}

// Dispatch 1: block 0 = pred hist+scan+scatter, block 1 = gt ditto,
//             blocks >=2 = zero the accumulator region.
__global__ __launch_bounds__(1024) void build_kernel(const float* __restrict__ pred,
                                                     const float* __restrict__ gt,
                                                     unsigned* __restrict__ startP,
                                                     unsigned* __restrict__ startG,
                                                     float4* __restrict__ sortP,
                                                     float4* __restrict__ sortG,
                                                     float* __restrict__ zero) {
    __shared__ unsigned h[NC];
    __shared__ unsigned ps[1024];
    if (blockIdx.x == 0) {
        hist_scan_scatter(pred, NP, startP, sortP, h, ps);
    } else if (blockIdx.x == 1) {
        hist_scan_scatter(gt, NG, startG, sortG, h, ps);
    } else {
        int i = (blockIdx.x - 2) * 1024 + threadIdx.x;
        if (i < N_ZERO) zero[i] = 0.0f;
    }
}

__device__ __forceinline__ float wave_sum(float x) {
    #pragma unroll
    for (int o = 32; o > 0; o >>= 1) x += __shfl_down(x, o, 64);
    return x;
}

__device__ __forceinline__ unsigned long long u64min(unsigned long long a,
                                                     unsigned long long b) {
    return a < b ? a : b;
}

// Group-parallel NN via expanding-box search over the cell-sorted array.
// Box radius r: (2r+1)^2 (z,y) rows; each row's x-cells are one CONTIGUOUS
// span [start[c0], start[c1+1]). Rows round-robin over 16 lanes; packed
// (d2bits<<32)|idx min-reduce == exact first-occurrence argmin. Terminate
// when best <= blo(r)^2 (blo = distance to nearest in-domain box face) or
// the box covers the grid. r=1 succeeds ~99.98%; rescans are idempotent.
// All loop conditions group-uniform -> shuffles safe.
__device__ __forceinline__ unsigned long long group_nn(int lane,
                                                       float px, float py, float pz,
                                                       const float4* __restrict__ S,
                                                       const unsigned* __restrict__ cstart) {
    int cx = cell_of(px), cy = cell_of(py), cz = cell_of(pz);
    unsigned long long best = 0xFFFFFFFFFFFFFFFFULL;
    for (int r = 1; ; ++r) {
        int w = 2 * r + 1;
        int nrows = w * w;
        int x0 = max(cx - r, 0), x1 = min(cx + r, GR - 1);
        unsigned long long lb = 0xFFFFFFFFFFFFFFFFULL;
        for (int k = lane; k < nrows; k += QL) {
            int z = cz + k / w - r, y = cy + k % w - r;
            if (z >= 0 && z < GR && y >= 0 && y < GR) {
                int rowbase = (z * GR + y) * GR;
                unsigned s0 = cstart[rowbase + x0];
                unsigned s1 = cstart[rowbase + x1 + 1];
                for (unsigned t = s0; t < s1; ++t) {
                    float4 q = S[t];
                    float ddx = px - q.x, ddy = py - q.y, ddz = pz - q.z;
                    float d2 = fmaf(ddx, ddx, fmaf(ddy, ddy, ddz*ddz));
                    unsigned long long key =
                        ((unsigned long long)__float_as_uint(d2) << 32) |
                        (unsigned)__float_as_int(q.w);
                    lb = u64min(lb, key);
                }
            }
        }
        best = u64min(best, lb);
        #pragma unroll
        for (int m = 1; m < QL; m <<= 1)
            best = u64min(best, (unsigned long long)__shfl_xor((long long)best, m, 64));
        bool covered = (cx - r <= 0) & (cx + r >= GR - 1) &
                       (cy - r <= 0) & (cy + r >= GR - 1) &
                       (cz - r <= 0) & (cz + r >= GR - 1);
        if (covered) break;
        float blo = 1.0e30f;
        if (cx - r > 0)      blo = fminf(blo, px - (float)(cx - r) * HCELL);
        if (cx + r < GR - 1) blo = fminf(blo, (float)(cx + r + 1) * HCELL - px);
        if (cy - r > 0)      blo = fminf(blo, py - (float)(cy - r) * HCELL);
        if (cy + r < GR - 1) blo = fminf(blo, (float)(cy + r + 1) * HCELL - py);
        if (cz - r > 0)      blo = fminf(blo, pz - (float)(cz - r) * HCELL);
        if (cz + r < GR - 1) blo = fminf(blo, (float)(cz + r + 1) * HCELL - pz);
        float bd2 = __uint_as_float((unsigned)(best >> 32));
        if (bd2 <= blo * blo) break;   // NaN (empty) -> false -> expand
    }
    return best;
}

// Dispatch 2: faces + pred-side NN (store keys) + gt-side NN (store partial
// col sums). The three families are independent; all depend only on d1.
#define FACE_BLOCKS ((NFG + NFP + 255) / 256)   // 158
#define D2_BLOCKS (FACE_BLOCKS + PRED_QBLOCKS + GT_QBLOCKS)  // 1420
__global__ __launch_bounds__(256) void work_kernel(const float* __restrict__ pred,
                                                   const int* __restrict__ pf,
                                                   const float* __restrict__ gt,
                                                   const int* __restrict__ gf,
                                                   const float4* __restrict__ sortP,
                                                   const float4* __restrict__ sortG,
                                                   const unsigned* __restrict__ startP,
                                                   const unsigned* __restrict__ startG,
                                                   unsigned long long* __restrict__ keys,
                                                   float* __restrict__ colpart,
                                                   float* __restrict__ gtn,
                                                   float* __restrict__ pnn,
                                                   float* __restrict__ nsum,
                                                   float* __restrict__ deg) {
    int b = blockIdx.x;
    if (b < FACE_BLOCKS) {
        int t = b * 256 + threadIdx.x;
        if (t < NFG) {
            int i0 = gf[3*t], i1 = gf[3*t+1], i2 = gf[3*t+2];
            float ax = gt[3*i0], ay = gt[3*i0+1], az = gt[3*i0+2];
            float bx = gt[3*i1], by = gt[3*i1+1], bz = gt[3*i1+2];
            float cx = gt[3*i2], cy = gt[3*i2+1], cz = gt[3*i2+2];
            float ux = bx-ax, uy = by-ay, uz = bz-az;
            float wx = cx-ax, wy = cy-ay, wz = cz-az;
            float nx = uy*wz - uz*wy, ny = uz*wx - ux*wz, nz = ux*wy - uy*wx;
            atomicAdd(&gtn[3*i0+0], nx); atomicAdd(&gtn[3*i0+1], ny); atomicAdd(&gtn[3*i0+2], nz);
            atomicAdd(&gtn[3*i1+0], nx); atomicAdd(&gtn[3*i1+1], ny); atomicAdd(&gtn[3*i1+2], nz);
            atomicAdd(&gtn[3*i2+0], nx); atomicAdd(&gtn[3*i2+1], ny); atomicAdd(&gtn[3*i2+2], nz);
        } else if (t < NFG + NFP) {
            int u = t - NFG;
            int i0 = pf[3*u], i1 = pf[3*u+1], i2 = pf[3*u+2];
            float ax = pred[3*i0], ay = pred[3*i0+1], az = pred[3*i0+2];
            float bx = pred[3*i1], by = pred[3*i1+1], bz = pred[3*i1+2];
            float cx = pred[3*i2], cy = pred[3*i2+1], cz = pred[3*i2+2];
            float ux = bx-ax, uy = by-ay, uz = bz-az;
            float wx = cx-ax, wy = cy-ay, wz = cz-az;
            float nx = uy*wz - uz*wy, ny = uz*wx - ux*wz, nz = ux*wy - uy*wx;
            atomicAdd(&pnn[3*i0+0], nx); atomicAdd(&pnn[3*i0+1], ny); atomicAdd(&pnn[3*i0+2], nz);
            atomicAdd(&pnn[3*i1+0], nx); atomicAdd(&pnn[3*i1+1], ny); atomicAdd(&pnn[3*i1+2], nz);
            atomicAdd(&pnn[3*i2+0], nx); atomicAdd(&pnn[3*i2+1], ny); atomicAdd(&pnn[3*i2+2], nz);
            atomicAdd(&nsum[3*i0+0], bx+cx); atomicAdd(&nsum[3*i0+1], by+cy); atomicAdd(&nsum[3*i0+2], bz+cz);
            atomicAdd(&nsum[3*i1+0], cx+ax); atomicAdd(&nsum[3*i1+1], cy+ay); atomicAdd(&nsum[3*i1+2], cz+az);
            atomicAdd(&nsum[3*i2+0], ax+bx); atomicAdd(&nsum[3*i2+1], ay+by); atomicAdd(&nsum[3*i2+2], az+bz);
            atomicAdd(&deg[i0], 2.0f); atomicAdd(&deg[i1], 2.0f); atomicAdd(&deg[i2], 2.0f);
        }
    } else if (b < FACE_BLOCKS + PRED_QBLOCKS) {
        int lane = threadIdx.x & (QL - 1);
        int group = threadIdx.x >> 4;
        int qid = (b - FACE_BLOCKS) * QPB + group;     // < 8192 exact
        float4 P = sortP[qid];
        unsigned long long key = group_nn(lane, P.x, P.y, P.z, sortG, startG);
        if (lane == 0) keys[qid] = key;
    } else {
        __shared__ float bsum;
        if (threadIdx.x == 0) bsum = 0.0f;
        __syncthreads();
        int lane = threadIdx.x & (QL - 1);
        int group = threadIdx.x >> 4;
        int qid = (b - FACE_BLOCKS - PRED_QBLOCKS) * QPB + group;  // < 12000 exact
        float4 Q = sortG[qid];
        unsigned long long key = group_nn(lane, Q.x, Q.y, Q.z, sortP, startP);
        float val = (lane == 0) ? __uint_as_float((unsigned)(key >> 32)) : 0.0f;
        float r = wave_sum(val);
        if ((threadIdx.x & 63) == 0) atomicAdd(&bsum, r);
        __syncthreads();
        if (threadIdx.x == 0)
            colpart[b - FACE_BLOCKS - PRED_QBLOCKS] = bsum;
    }
}

// Dispatch 3: ONE block. Per-pred epilogue (normal MSE, laplacian, focal,
// row-min sum) over 8192 verts + gt partial reduction + final combine.
__global__ __launch_bounds__(256) void finalize_kernel(const float* __restrict__ relpos,
                                                       const int* __restrict__ label,
                                                       const float4* __restrict__ sortP,
                                                       const unsigned long long* __restrict__ keys,
                                                       const float* __restrict__ colpart,
                                                       const float* __restrict__ pnn,
                                                       const float* __restrict__ gtn,
                                                       const float* __restrict__ nsum,
                                                       const float* __restrict__ deg,
                                                       float* __restrict__ out) {
    float s_row = 0.f, s_sse = 0.f, s_lap = 0.f, s_pc = 0.f, s_sx = 0.f, s_sy = 0.f, s_col = 0.f;
    for (int i = threadIdx.x; i < NP; i += 256) {
        float4 P = sortP[i];
        float px = P.x, py = P.y, pz = P.z;
        int v = __float_as_int(P.w);
        unsigned long long key = keys[i];
        s_row += __uint_as_float((unsigned)(key >> 32));
        int nearest = (int)(unsigned)(key & 0xffffffffu);

        float ax = pnn[3*v], ay = pnn[3*v+1], az = pnn[3*v+2];
        float an = fmaxf(sqrtf(ax*ax + ay*ay + az*az), EPSF);
        float gx = gtn[3*nearest], gy = gtn[3*nearest+1], gz = gtn[3*nearest+2];
        float gn = fmaxf(sqrtf(gx*gx + gy*gy + gz*gz), EPSF);
        float nx = ax/an - gx/gn, ny = ay/an - gy/gn, nz = az/an - gz/gn;
        s_sse += nx*nx + ny*ny + nz*nz;

        float d = fmaxf(deg[v], 1.0f);
        float lx = nsum[3*v]/d - px, ly = nsum[3*v+1]/d - py, lz = nsum[3*v+2]/d - pz;
        s_lap += sqrtf(lx*lx + ly*ly + lz*lz);

        int ix = (int)rintf(px * 95.0f), iy = (int)rintf(py * 95.0f), iz = (int)rintf(pz * 95.0f);
        bool inb = (ix >= 0) & (ix < 96) & (iy >= 0) & (iy < 96) & (iz >= 0) & (iz < 96);
        int ixc = min(max(ix, 0), 95), iyc = min(max(iy, 0), 95), izc = min(max(iz, 0), 95);
        bool pos = inb && (label[(izc*96 + iyc)*96 + ixc] == 1);

        float p = fminf(fmaxf(relpos[v], EPSF), 1.0f - EPSF);
        float om = 1.0f - p;
        if (pos) { s_pc += 1.0f; s_sx += om*om*logf(p); }
        else     { s_sy += p*p*logf(om); }
    }
    for (int j = threadIdx.x; j < GT_QBLOCKS; j += 256) s_col += colpart[j];

    s_row = wave_sum(s_row); s_sse = wave_sum(s_sse); s_lap = wave_sum(s_lap);
    s_pc = wave_sum(s_pc); s_sx = wave_sum(s_sx); s_sy = wave_sum(s_sy);
    s_col = wave_sum(s_col);
    __shared__ float acc[7];
    if (threadIdx.x < 7) acc[threadIdx.x] = 0.0f;
    __syncthreads();
    if ((threadIdx.x & 63) == 0) {
        atomicAdd(&acc[0], s_row); atomicAdd(&acc[1], s_sse); atomicAdd(&acc[2], s_lap);
        atomicAdd(&acc[3], s_pc);  atomicAdd(&acc[4], s_sx);  atomicAdd(&acc[5], s_sy);
        atomicAdd(&acc[6], s_col);
    }
    __syncthreads();
    if (threadIdx.x == 0) {
        float tot = (float)NP;
        float alpha = (tot - acc[3]) / (tot + EPSF);
        float spatial = (-alpha * acc[4] - (1.0f - alpha) * acc[5]) / (tot + EPSF);
        float distance = acc[0] / (float)NP + acc[6] / (float)NG;
        float normal = acc[1] / (float)(NP * 3);
        float lapm = acc[2] / (float)NP;
        out[0] = spatial + 1.0f * distance + 0.01f * normal + 0.1f * lapm;
    }
}

extern "C" void kernel_launch(void* const* d_in, const int* in_sizes, int n_in,
                              void* d_out, int out_size, void* d_ws, size_t ws_size,
                              hipStream_t stream) {
    const float* pred   = (const float*)d_in[0];   // [8192,3]
    const float* relpos = (const float*)d_in[1];   // [8192]
    const float* gt     = (const float*)d_in[2];   // [12000,3]
    const int*   pfaces = (const int*)d_in[3];     // [16384,3]
    const int*   gfaces = (const int*)d_in[4];     // [24000,3]
    const int*   label  = (const int*)d_in[5];     // [1,1,96,96,96]
    float* out = (float*)d_out;

    char* ws = (char*)d_ws;
    unsigned* startP  = (unsigned*)(ws + OFF_STARTP);
    unsigned* startG  = (unsigned*)(ws + OFF_STARTG);
    float4*   sortP   = (float4*)(ws + OFF_SORTP);
    float4*   sortG   = (float4*)(ws + OFF_SORTG);
    unsigned long long* keys = (unsigned long long*)(ws + OFF_KEYS);
    float*    colpart = (float*)(ws + OFF_COLP);
    float*    gtn     = (float*)(ws + OFF_GTN);
    float*    pnn     = (float*)(ws + OFF_PNN);
    float*    nsum    = (float*)(ws + OFF_NSUM);
    float*    deg     = (float*)(ws + OFF_DEG);

    // d1: hist+scan+scatter (blocks 0,1) || zero accumulators (blocks 2..)
    int zero_blocks = (N_ZERO + 1023) / 1024;      // 92
    hipLaunchKernelGGL(build_kernel, dim3(2 + zero_blocks), dim3(1024), 0, stream,
                       pred, gt, startP, startG, sortP, sortG, gtn);
    // d2: faces + pred NN (keys) + gt NN (col partials)
    hipLaunchKernelGGL(work_kernel, dim3(D2_BLOCKS), dim3(256), 0, stream,
                       pred, pfaces, gt, gfaces, sortP, sortG, startP, startG,
                       keys, colpart, gtn, pnn, nsum, deg);
    // d3: single-block epilogue + combine
    hipLaunchKernelGGL(finalize_kernel, dim3(1), dim3(256), 0, stream,
                       relpos, label, sortP, keys, colpart,
                       pnn, gtn, nsum, deg, out);
}

// Round 10
// 123.157 us; speedup vs baseline: 1.4325x; 1.4325x over previous
//
#include <hip/hip_runtime.h>
#include <math.h>

// Problem constants (fixed by setup_inputs)
#define NP 8192      // pred vertices
#define NG 12000     // gt vertices
#define NFP 16384    // pred faces
#define NFG 24000    // gt faces
#define EPSF 1e-6f

// uniform grid for NN: 16^3 cells over [0,1]^3, ~3 gt / ~2 pred per cell
#define GR 16
#define NC (GR*GR*GR)        // 4096
#define HCELL 0.0625f        // 1/16, exact power of two
#define QL 16                // lanes cooperating per NN query
#define QPB (256 / QL)       // 16 queries per block
#define PRED_QBLOCKS (NP / QPB)               // 512
#define GT_QBLOCKS (NG / QPB)                 // 750

// ---- workspace layout (bytes) ----
static constexpr size_t OFF_STARTP = 0;        // (NC+1) u32 cell start (pred), [NC]=NP
static constexpr size_t OFF_STARTG = 16640;    // (NC+1) u32 cell start (gt), [NC]=NG
static constexpr size_t OFF_SORTP  = 33280;    // 8192  float4 (x,y,z,idx-as-float-bits)
static constexpr size_t OFF_SORTG  = 164352;   // 12000 float4
static constexpr size_t OFF_KEYS   = 356352;   // 8192 u64 pred NN keys (d2bits<<32)|idx
static constexpr size_t OFF_COLP   = 421888;   // 750 f32 gt-side per-block partials
static constexpr size_t OFF_GTN    = 424960;   // NG*3 f32 gt normal accum (raw)
static constexpr size_t OFF_PNN    = 568960;   // NP*3 f32 pred normal accum
static constexpr size_t OFF_NSUM   = 667264;   // NP*3 f32 laplacian neighbor sum
static constexpr size_t OFF_DEG    = 765568;   // NP   f32 laplacian degree
static constexpr size_t OFF_TICK   = 798336;   // 1 u32 ticket (inside zero span)
static constexpr size_t OFF_EPART  = 798400;   // 32 x 8 f32 epilogue partials (plain stores)
#define N_ZERO 93345   // floats gtn..deg + ticket (contiguous from OFF_GTN)

__device__ __forceinline__ int cell_of(float x) {
    int c = (int)(x * (float)GR);
    return min(max(c, 0), GR - 1);
}

// histogram + exclusive scan + cell-ordered scatter of one point set
// (one 1024-thread block; LDS h[] doubles as scan result then scatter cursor)
__device__ __forceinline__ void hist_scan_scatter(const float* __restrict__ pts, int n,
                                                  unsigned* __restrict__ start,
                                                  float4* __restrict__ sorted,
                                                  unsigned* h, unsigned* ps) {
    int t = threadIdx.x;
    for (int i = t; i < NC; i += 1024) h[i] = 0u;
    __syncthreads();
    for (int i = t; i < n; i += 1024) {
        int c = (cell_of(pts[3*i+2]) * GR + cell_of(pts[3*i+1])) * GR + cell_of(pts[3*i]);
        atomicAdd(&h[c], 1u);
    }
    __syncthreads();
    unsigned a0 = h[4*t], a1 = h[4*t+1], a2 = h[4*t+2], a3 = h[4*t+3];
    unsigned tsum = a0 + a1 + a2 + a3;
    ps[t] = tsum; __syncthreads();
    for (int off = 1; off < 1024; off <<= 1) {
        unsigned v = (t >= off) ? ps[t - off] : 0u;
        __syncthreads();
        ps[t] += v;
        __syncthreads();
    }
    unsigned ex = ps[t] - tsum;
    h[4*t] = ex; h[4*t+1] = ex + a0; h[4*t+2] = ex + a0 + a1; h[4*t+3] = ex + a0 + a1 + a2;
    __syncthreads();
    for (int i = t; i < NC; i += 1024) start[i] = h[i];
    if (t == 0) start[NC] = (unsigned)n;   // end sentinel: end[c] == start[c+1]
    __syncthreads();
    // scatter using h as live cursors (start[] already safely in global)
    for (int i = t; i < n; i += 1024) {
        float x = pts[3*i], y = pts[3*i+1], z = pts[3*i+2];
        int c = (cell_of(z) * GR + cell_of(y)) * GR + cell_of(x);
        unsigned pos = atomicAdd(&h[c], 1u);
        sorted[pos] = make_float4(x, y, z, __int_as_float(i));
    }
}

// Dispatch 1: block 0 = pred hist+scan+scatter, block 1 = gt ditto,
//             blocks >=2 = zero the accumulator region (incl. ticket).
__global__ __launch_bounds__(1024) void build_kernel(const float* __restrict__ pred,
                                                     const float* __restrict__ gt,
                                                     unsigned* __restrict__ startP,
                                                     unsigned* __restrict__ startG,
                                                     float4* __restrict__ sortP,
                                                     float4* __restrict__ sortG,
                                                     float* __restrict__ zero) {
    __shared__ unsigned h[NC];
    __shared__ unsigned ps[1024];
    if (blockIdx.x == 0) {
        hist_scan_scatter(pred, NP, startP, sortP, h, ps);
    } else if (blockIdx.x == 1) {
        hist_scan_scatter(gt, NG, startG, sortG, h, ps);
    } else {
        int i = (blockIdx.x - 2) * 1024 + threadIdx.x;
        if (i < N_ZERO) zero[i] = 0.0f;
    }
}

__device__ __forceinline__ float wave_sum(float x) {
    #pragma unroll
    for (int o = 32; o > 0; o >>= 1) x += __shfl_down(x, o, 64);
    return x;
}

__device__ __forceinline__ unsigned long long u64min(unsigned long long a,
                                                     unsigned long long b) {
    return a < b ? a : b;
}

// Group-parallel NN via expanding-box search over the cell-sorted array.
// Box radius r: (2r+1)^2 (z,y) rows; each row's x-cells are one CONTIGUOUS
// span [start[c0], start[c1+1]). Rows round-robin over 16 lanes; packed
// (d2bits<<32)|idx min-reduce == exact first-occurrence argmin. Terminate
// when best <= blo(r)^2 (blo = distance to nearest in-domain box face) or
// the box covers the grid. r=1 succeeds ~99.98%; rescans are idempotent.
// All loop conditions group-uniform -> shuffles safe.
__device__ __forceinline__ unsigned long long group_nn(int lane,
                                                       float px, float py, float pz,
                                                       const float4* __restrict__ S,
                                                       const unsigned* __restrict__ cstart) {
    int cx = cell_of(px), cy = cell_of(py), cz = cell_of(pz);
    unsigned long long best = 0xFFFFFFFFFFFFFFFFULL;
    for (int r = 1; ; ++r) {
        int w = 2 * r + 1;
        int nrows = w * w;
        int x0 = max(cx - r, 0), x1 = min(cx + r, GR - 1);
        unsigned long long lb = 0xFFFFFFFFFFFFFFFFULL;
        for (int k = lane; k < nrows; k += QL) {
            int z = cz + k / w - r, y = cy + k % w - r;
            if (z >= 0 && z < GR && y >= 0 && y < GR) {
                int rowbase = (z * GR + y) * GR;
                unsigned s0 = cstart[rowbase + x0];
                unsigned s1 = cstart[rowbase + x1 + 1];
                for (unsigned t = s0; t < s1; ++t) {
                    float4 q = S[t];
                    float ddx = px - q.x, ddy = py - q.y, ddz = pz - q.z;
                    float d2 = fmaf(ddx, ddx, fmaf(ddy, ddy, ddz*ddz));
                    unsigned long long key =
                        ((unsigned long long)__float_as_uint(d2) << 32) |
                        (unsigned)__float_as_int(q.w);
                    lb = u64min(lb, key);
                }
            }
        }
        best = u64min(best, lb);
        #pragma unroll
        for (int m = 1; m < QL; m <<= 1)
            best = u64min(best, (unsigned long long)__shfl_xor((long long)best, m, 64));
        bool covered = (cx - r <= 0) & (cx + r >= GR - 1) &
                       (cy - r <= 0) & (cy + r >= GR - 1) &
                       (cz - r <= 0) & (cz + r >= GR - 1);
        if (covered) break;
        float blo = 1.0e30f;
        if (cx - r > 0)      blo = fminf(blo, px - (float)(cx - r) * HCELL);
        if (cx + r < GR - 1) blo = fminf(blo, (float)(cx + r + 1) * HCELL - px);
        if (cy - r > 0)      blo = fminf(blo, py - (float)(cy - r) * HCELL);
        if (cy + r < GR - 1) blo = fminf(blo, (float)(cy + r + 1) * HCELL - py);
        if (cz - r > 0)      blo = fminf(blo, pz - (float)(cz - r) * HCELL);
        if (cz + r < GR - 1) blo = fminf(blo, (float)(cz + r + 1) * HCELL - pz);
        float bd2 = __uint_as_float((unsigned)(best >> 32));
        if (bd2 <= blo * blo) break;   // NaN (empty) -> false -> expand
    }
    return best;
}

// Dispatch 2: faces + pred-side NN (store keys) + gt-side NN (store partial
// col sums). The three families are independent; all depend only on d1.
#define FACE_BLOCKS ((NFG + NFP + 255) / 256)   // 158
#define D2_BLOCKS (FACE_BLOCKS + PRED_QBLOCKS + GT_QBLOCKS)  // 1420
__global__ __launch_bounds__(256) void work_kernel(const float* __restrict__ pred,
                                                   const int* __restrict__ pf,
                                                   const float* __restrict__ gt,
                                                   const int* __restrict__ gf,
                                                   const float4* __restrict__ sortP,
                                                   const float4* __restrict__ sortG,
                                                   const unsigned* __restrict__ startP,
                                                   const unsigned* __restrict__ startG,
                                                   unsigned long long* __restrict__ keys,
                                                   float* __restrict__ colpart,
                                                   float* __restrict__ gtn,
                                                   float* __restrict__ pnn,
                                                   float* __restrict__ nsum,
                                                   float* __restrict__ deg) {
    int b = blockIdx.x;
    if (b < FACE_BLOCKS) {
        int t = b * 256 + threadIdx.x;
        if (t < NFG) {
            int i0 = gf[3*t], i1 = gf[3*t+1], i2 = gf[3*t+2];
            float ax = gt[3*i0], ay = gt[3*i0+1], az = gt[3*i0+2];
            float bx = gt[3*i1], by = gt[3*i1+1], bz = gt[3*i1+2];
            float cx = gt[3*i2], cy = gt[3*i2+1], cz = gt[3*i2+2];
            float ux = bx-ax, uy = by-ay, uz = bz-az;
            float wx = cx-ax, wy = cy-ay, wz = cz-az;
            float nx = uy*wz - uz*wy, ny = uz*wx - ux*wz, nz = ux*wy - uy*wx;
            atomicAdd(&gtn[3*i0+0], nx); atomicAdd(&gtn[3*i0+1], ny); atomicAdd(&gtn[3*i0+2], nz);
            atomicAdd(&gtn[3*i1+0], nx); atomicAdd(&gtn[3*i1+1], ny); atomicAdd(&gtn[3*i1+2], nz);
            atomicAdd(&gtn[3*i2+0], nx); atomicAdd(&gtn[3*i2+1], ny); atomicAdd(&gtn[3*i2+2], nz);
        } else if (t < NFG + NFP) {
            int u = t - NFG;
            int i0 = pf[3*u], i1 = pf[3*u+1], i2 = pf[3*u+2];
            float ax = pred[3*i0], ay = pred[3*i0+1], az = pred[3*i0+2];
            float bx = pred[3*i1], by = pred[3*i1+1], bz = pred[3*i1+2];
            float cx = pred[3*i2], cy = pred[3*i2+1], cz = pred[3*i2+2];
            float ux = bx-ax, uy = by-ay, uz = bz-az;
            float wx = cx-ax, wy = cy-ay, wz = cz-az;
            float nx = uy*wz - uz*wy, ny = uz*wx - ux*wz, nz = ux*wy - uy*wx;
            atomicAdd(&pnn[3*i0+0], nx); atomicAdd(&pnn[3*i0+1], ny); atomicAdd(&pnn[3*i0+2], nz);
            atomicAdd(&pnn[3*i1+0], nx); atomicAdd(&pnn[3*i1+1], ny); atomicAdd(&pnn[3*i1+2], nz);
            atomicAdd(&pnn[3*i2+0], nx); atomicAdd(&pnn[3*i2+1], ny); atomicAdd(&pnn[3*i2+2], nz);
            atomicAdd(&nsum[3*i0+0], bx+cx); atomicAdd(&nsum[3*i0+1], by+cy); atomicAdd(&nsum[3*i0+2], bz+cz);
            atomicAdd(&nsum[3*i1+0], cx+ax); atomicAdd(&nsum[3*i1+1], cy+ay); atomicAdd(&nsum[3*i1+2], cz+az);
            atomicAdd(&nsum[3*i2+0], ax+bx); atomicAdd(&nsum[3*i2+1], ay+by); atomicAdd(&nsum[3*i2+2], az+bz);
            atomicAdd(&deg[i0], 2.0f); atomicAdd(&deg[i1], 2.0f); atomicAdd(&deg[i2], 2.0f);
        }
    } else if (b < FACE_BLOCKS + PRED_QBLOCKS) {
        int lane = threadIdx.x & (QL - 1);
        int group = threadIdx.x >> 4;
        int qid = (b - FACE_BLOCKS) * QPB + group;     // < 8192 exact
        float4 P = sortP[qid];
        unsigned long long key = group_nn(lane, P.x, P.y, P.z, sortG, startG);
        if (lane == 0) keys[qid] = key;
    } else {
        __shared__ float bsum;
        if (threadIdx.x == 0) bsum = 0.0f;
        __syncthreads();
        int lane = threadIdx.x & (QL - 1);
        int group = threadIdx.x >> 4;
        int qid = (b - FACE_BLOCKS - PRED_QBLOCKS) * QPB + group;  // < 12000 exact
        float4 Q = sortG[qid];
        unsigned long long key = group_nn(lane, Q.x, Q.y, Q.z, sortP, startP);
        float val = (lane == 0) ? __uint_as_float((unsigned)(key >> 32)) : 0.0f;
        float r = wave_sum(val);
        if ((threadIdx.x & 63) == 0) atomicAdd(&bsum, r);
        __syncthreads();
        if (threadIdx.x == 0)
            colpart[b - FACE_BLOCKS - PRED_QBLOCKS] = bsum;
    }
}

// Dispatch 3: DISTRIBUTED epilogue — 32 blocks, one pred vertex per thread
// (independent scattered loads pipeline across 8192 threads / 32 CUs), plus
// colpart slice fold; per-block 7-float partial row; last block (ticket)
// combines via device-scope atomic reads and writes out[0].
#define EPI_BLOCKS 32
__global__ __launch_bounds__(256) void epilogue_kernel(const float* __restrict__ relpos,
                                                       const int* __restrict__ label,
                                                       const float4* __restrict__ sortP,
                                                       const unsigned long long* __restrict__ keys,
                                                       const float* __restrict__ colpart,
                                                       const float* __restrict__ pnn,
                                                       const float* __restrict__ gtn,
                                                       const float* __restrict__ nsum,
                                                       const float* __restrict__ deg,
                                                       float* __restrict__ epart,
                                                       unsigned* __restrict__ ticket,
                                                       float* __restrict__ out) {
    int i = blockIdx.x * 256 + threadIdx.x;     // < 8192 exact
    float4 P = sortP[i];
    float px = P.x, py = P.y, pz = P.z;
    int v = __float_as_int(P.w);
    unsigned long long key = keys[i];
    float s_row = __uint_as_float((unsigned)(key >> 32));
    int nearest = (int)(unsigned)(key & 0xffffffffu);

    float ax = pnn[3*v], ay = pnn[3*v+1], az = pnn[3*v+2];
    float an = fmaxf(sqrtf(ax*ax + ay*ay + az*az), EPSF);
    float gx = gtn[3*nearest], gy = gtn[3*nearest+1], gz = gtn[3*nearest+2];
    float gn = fmaxf(sqrtf(gx*gx + gy*gy + gz*gz), EPSF);
    float nx = ax/an - gx/gn, ny = ay/an - gy/gn, nz = az/an - gz/gn;
    float s_sse = nx*nx + ny*ny + nz*nz;

    float d = fmaxf(deg[v], 1.0f);
    float lx = nsum[3*v]/d - px, ly = nsum[3*v+1]/d - py, lz = nsum[3*v+2]/d - pz;
    float s_lap = sqrtf(lx*lx + ly*ly + lz*lz);

    int ix = (int)rintf(px * 95.0f), iy = (int)rintf(py * 95.0f), iz = (int)rintf(pz * 95.0f);
    bool inb = (ix >= 0) & (ix < 96) & (iy >= 0) & (iy < 96) & (iz >= 0) & (iz < 96);
    int ixc = min(max(ix, 0), 95), iyc = min(max(iy, 0), 95), izc = min(max(iz, 0), 95);
    bool pos = inb && (label[(izc*96 + iyc)*96 + ixc] == 1);

    float p = fminf(fmaxf(relpos[v], EPSF), 1.0f - EPSF);
    float om = 1.0f - p;
    float s_pc = 0.f, s_sx = 0.f, s_sy = 0.f;
    if (pos) { s_pc = 1.0f; s_sx = om*om*logf(p); }
    else     { s_sy = p*p*logf(om); }

    float s_col = (i < GT_QBLOCKS) ? colpart[i] : 0.0f;   // blocks 0..2 fold gt partials

    s_row = wave_sum(s_row); s_sse = wave_sum(s_sse); s_lap = wave_sum(s_lap);
    s_pc = wave_sum(s_pc); s_sx = wave_sum(s_sx); s_sy = wave_sum(s_sy);
    s_col = wave_sum(s_col);
    __shared__ float acc[7];
    if (threadIdx.x < 7) acc[threadIdx.x] = 0.0f;
    __syncthreads();
    if ((threadIdx.x & 63) == 0) {
        atomicAdd(&acc[0], s_row); atomicAdd(&acc[1], s_sse); atomicAdd(&acc[2], s_lap);
        atomicAdd(&acc[3], s_pc);  atomicAdd(&acc[4], s_sx);  atomicAdd(&acc[5], s_sy);
        atomicAdd(&acc[6], s_col);
    }
    __syncthreads();
    if (threadIdx.x < 7)
        epart[(size_t)blockIdx.x * 8 + threadIdx.x] = acc[threadIdx.x];

    // ticket combine: 32 same-address atomics total (cheap), device-scope reads
    __threadfence();
    __shared__ int is_last;
    if (threadIdx.x == 0) {
        unsigned t = atomicAdd(ticket, 1u);
        is_last = (t == EPI_BLOCKS - 1) ? 1 : 0;
    }
    __syncthreads();
    if (is_last) {
        int row = threadIdx.x >> 3, col = threadIdx.x & 7;   // 32 rows x 8
        float val = (row < EPI_BLOCKS && col < 7)
                  ? atomicAdd(&epart[(size_t)row * 8 + col], 0.0f) : 0.0f;
        __shared__ float fin[7];
        if (threadIdx.x < 7) fin[threadIdx.x] = 0.0f;
        __syncthreads();
        if (col < 7 && row < EPI_BLOCKS) atomicAdd(&fin[col], val);
        __syncthreads();
        if (threadIdx.x == 0) {
            float tot = (float)NP;
            float alpha = (tot - fin[3]) / (tot + EPSF);
            float spatial = (-alpha * fin[4] - (1.0f - alpha) * fin[5]) / (tot + EPSF);
            float distance = fin[0] / (float)NP + fin[6] / (float)NG;
            float normal = fin[1] / (float)(NP * 3);
            float lapm = fin[2] / (float)NP;
            out[0] = spatial + 1.0f * distance + 0.01f * normal + 0.1f * lapm;
        }
    }
}

extern "C" void kernel_launch(void* const* d_in, const int* in_sizes, int n_in,
                              void* d_out, int out_size, void* d_ws, size_t ws_size,
                              hipStream_t stream) {
    const float* pred   = (const float*)d_in[0];   // [8192,3]
    const float* relpos = (const float*)d_in[1];   // [8192]
    const float* gt     = (const float*)d_in[2];   // [12000,3]
    const int*   pfaces = (const int*)d_in[3];     // [16384,3]
    const int*   gfaces = (const int*)d_in[4];     // [24000,3]
    const int*   label  = (const int*)d_in[5];     // [1,1,96,96,96]
    float* out = (float*)d_out;

    char* ws = (char*)d_ws;
    unsigned* startP  = (unsigned*)(ws + OFF_STARTP);
    unsigned* startG  = (unsigned*)(ws + OFF_STARTG);
    float4*   sortP   = (float4*)(ws + OFF_SORTP);
    float4*   sortG   = (float4*)(ws + OFF_SORTG);
    unsigned long long* keys = (unsigned long long*)(ws + OFF_KEYS);
    float*    colpart = (float*)(ws + OFF_COLP);
    float*    gtn     = (float*)(ws + OFF_GTN);
    float*    pnn     = (float*)(ws + OFF_PNN);
    float*    nsum    = (float*)(ws + OFF_NSUM);
    float*    deg     = (float*)(ws + OFF_DEG);
    unsigned* ticket  = (unsigned*)(ws + OFF_TICK);
    float*    epart   = (float*)(ws + OFF_EPART);

    // d1: hist+scan+scatter (blocks 0,1) || zero accumulators+ticket (blocks 2..)
    int zero_blocks = (N_ZERO + 1023) / 1024;      // 92
    hipLaunchKernelGGL(build_kernel, dim3(2 + zero_blocks), dim3(1024), 0, stream,
                       pred, gt, startP, startG, sortP, sortG, gtn);
    // d2: faces + pred NN (keys) + gt NN (col partials)
    hipLaunchKernelGGL(work_kernel, dim3(D2_BLOCKS), dim3(256), 0, stream,
                       pred, pfaces, gt, gfaces, sortP, sortG, startP, startG,
                       keys, colpart, gtn, pnn, nsum, deg);
    // d3: distributed epilogue + ticket combine
    hipLaunchKernelGGL(epilogue_kernel, dim3(EPI_BLOCKS), dim3(256), 0, stream,
                       relpos, label, sortP, keys, colpart,
                       pnn, gtn, nsum, deg, epart, ticket, out);
}